// Round 11
// baseline (76.145 us; speedup 1.0000x reference)
//
#include <hip/hip_runtime.h>
#include <hip/hip_bf16.h>
#include <math.h>

#define NN 55
#define KK 8192
#define OO 8192

using bf16x8 = __attribute__((ext_vector_type(8))) __bf16;
using f32x4  = __attribute__((ext_vector_type(4))) float;

__device__ inline bf16x8 cvt8(f32x4 lo, f32x4 hi) {
    bf16x8 v;
    v[0] = (__bf16)lo[0]; v[1] = (__bf16)lo[1];
    v[2] = (__bf16)lo[2]; v[3] = (__bf16)lo[3];
    v[4] = (__bf16)hi[0]; v[5] = (__bf16)hi[1];
    v[6] = (__bf16)hi[2]; v[7] = (__bf16)hi[3];
    return v;
}

// Kernel 1: x [55,8192] f32 -> xb [64,8192] bf16, rows 55..63 zeroed.
__global__ __launch_bounds__(256)
void cvt_x(const float* __restrict__ xg, __bf16* __restrict__ xb) {
    const int idx = blockIdx.x * 256 + threadIdx.x;
    const int row = idx >> 10;
    const int c8  = (idx & 1023) * 8;
    bf16x8 v = {};
    if (row < NN) {
        const float* p = xg + (size_t)row * KK + c8;
        v = cvt8(*(const f32x4*)p, *(const f32x4*)(p + 4));
    }
    *(bf16x8*)(xb + (size_t)row * KK + c8) = v;
}

#define WAITVM(N) asm volatile("s_waitcnt vmcnt(" #N ")" ::: "memory")

struct WSlot { f32x4 a, b, c, d; };   // row r lo/hi, row r+16 lo/hi
struct ASlot { bf16x8 a, b, c, d; };  // m-tiles 0..3

// out = elu(x @ W^T + b).  BARRIER-FREE register pipeline (R10 + slot fix).
// 256 blocks x 512 threads (8 waves), o-tile 32. Wave w owns K range
// [w*1024,(w+1)*1024): 32 k-steps ("windows") of 32. W (zero reuse) loaded
// DIRECTLY to registers as per-lane f32x4 pairs (exactly the 16x16x32
// B-fragment layout); A from bf16 xb. 4 slots, 3 windows in flight:
// line s = [WAITVM(16); COMP(slot s%4); ISSUE(window s+3 -> slot (s+3)%4)].
// No s_barrier / no LDS in the main loop -- each wave self-paces; LDS used
// only for the final cross-wave k-reduction.
__global__ __launch_bounds__(512, 2)
void gat_gemm_elu11(const __bf16* __restrict__ xb,
                    const float* __restrict__ wg,
                    const float* __restrict__ bg,
                    float* __restrict__ outg) {
    __shared__ float red[8 * 2048];   // 64 KiB

    const int tid  = threadIdx.x;
    const int lane = tid & 63;
    const int w    = tid >> 6;
    const int r    = lane & 15;
    const int q    = lane >> 4;
    const int obase = blockIdx.x * 32;

    const int kb = w * 1024 + q * 8;
    const float*  wp0 = wg + (size_t)(obase + r) * KK + kb;   // o-sub 0
    const float*  wp1 = wp0 + (size_t)16 * KK;                // o-sub 1
    const __bf16* ap0 = xb + (size_t)r * KK + kb;             // m-tile 0
    const __bf16* ap1 = ap0 + (size_t)16 * KK;
    const __bf16* ap2 = ap0 + (size_t)32 * KK;
    const __bf16* ap3 = ap0 + (size_t)48 * KK;

    f32x4 acc0[4] = {};
    f32x4 acc1[4] = {};
    WSlot w0, w1, w2, w3;
    ASlot a0, a1, a2, a3;

// issue window at offset JW k-steps from current bases (8 VMEM instrs)
#define ISSUE(WS, AS, JW) do {                                               \
    WS.a = *(const f32x4*) ((const char*)wp0 + (JW) * 128);                  \
    WS.b = *(const f32x4*) ((const char*)wp0 + (JW) * 128 + 16);             \
    WS.c = *(const f32x4*) ((const char*)wp1 + (JW) * 128);                  \
    WS.d = *(const f32x4*) ((const char*)wp1 + (JW) * 128 + 16);             \
    AS.a = *(const bf16x8*)((const char*)ap0 + (JW) * 64);                   \
    AS.b = *(const bf16x8*)((const char*)ap1 + (JW) * 64);                   \
    AS.c = *(const bf16x8*)((const char*)ap2 + (JW) * 64);                   \
    AS.d = *(const bf16x8*)((const char*)ap3 + (JW) * 64);                   \
} while (0)

#define COMP(WS, AS) do {                                                    \
    const bf16x8 b0 = cvt8(WS.a, WS.b);                                      \
    const bf16x8 b1 = cvt8(WS.c, WS.d);                                      \
    acc0[0] = __builtin_amdgcn_mfma_f32_16x16x32_bf16(AS.a, b0, acc0[0], 0, 0, 0); \
    acc1[0] = __builtin_amdgcn_mfma_f32_16x16x32_bf16(AS.a, b1, acc1[0], 0, 0, 0); \
    acc0[1] = __builtin_amdgcn_mfma_f32_16x16x32_bf16(AS.b, b0, acc0[1], 0, 0, 0); \
    acc1[1] = __builtin_amdgcn_mfma_f32_16x16x32_bf16(AS.b, b1, acc1[1], 0, 0, 0); \
    acc0[2] = __builtin_amdgcn_mfma_f32_16x16x32_bf16(AS.c, b0, acc0[2], 0, 0, 0); \
    acc1[2] = __builtin_amdgcn_mfma_f32_16x16x32_bf16(AS.c, b1, acc1[2], 0, 0, 0); \
    acc0[3] = __builtin_amdgcn_mfma_f32_16x16x32_bf16(AS.d, b0, acc0[3], 0, 0, 0); \
    acc1[3] = __builtin_amdgcn_mfma_f32_16x16x32_bf16(AS.d, b1, acc1[3], 0, 0, 0); \
} while (0)

    // prologue: windows 0,1,2 -> slots 0,1,2 (24 VMEM ops in flight)
    ISSUE(w0, a0, 0);
    ISSUE(w1, a1, 1);
    ISSUE(w2, a2, 2);

    // steady: groups of 4 windows; base advances 4 k-steps per group.
    // Window 4g+j computed from slot j; window s+3 issued into slot (s+3)%4.
#pragma unroll 1
    for (int g = 0; g < 7; ++g) {
        WAITVM(16); COMP(w0, a0); ISSUE(w3, a3, 3);
        WAITVM(16); COMP(w1, a1); ISSUE(w0, a0, 4);
        WAITVM(16); COMP(w2, a2); ISSUE(w1, a1, 5);
        WAITVM(16); COMP(w3, a3); ISSUE(w2, a2, 6);
        wp0 += 128; wp1 += 128;                          // +4 k-steps (f32)
        ap0 += 128; ap1 += 128; ap2 += 128; ap3 += 128;  // +4 k-steps (bf16)
    }
    // tail: windows 28..31 (slots w0,w1,w2 hold 28,29,30; issue 31 -> w3)
    WAITVM(16); COMP(w0, a0); ISSUE(w3, a3, 3);
    WAITVM(16); COMP(w1, a1);
    WAITVM(8);  COMP(w2, a2);
    WAITVM(0);  COMP(w3, a3);

    // cross-wave k-reduction (LDS used only here)
#pragma unroll
    for (int mt = 0; mt < 4; ++mt) {
#pragma unroll
        for (int e = 0; e < 4; ++e) {
            const int row = mt * 16 + q * 4 + e;
            red[w * 2048 + row * 32 + r]      = acc0[mt][e];
            red[w * 2048 + row * 32 + 16 + r] = acc1[mt][e];
        }
    }
    __syncthreads();

    for (int i = tid; i < 2048; i += 512) {
        float ssum = 0.f;
#pragma unroll
        for (int ww = 0; ww < 8; ++ww) ssum += red[ww * 2048 + i];
        const int row = i >> 5;
        const int col = i & 31;
        const float v = ssum + bg[obase + col];
        const float res = (v > 0.f) ? v : expm1f(v);
        if (row < NN) outg[(size_t)row * OO + obase + col] = res;
    }
#undef ISSUE
#undef COMP
}

extern "C" void kernel_launch(void* const* d_in, const int* in_sizes, int n_in,
                              void* d_out, int out_size, void* d_ws, size_t ws_size,
                              hipStream_t stream) {
    const float* x  = (const float*)d_in[0];
    const float* W1 = (const float*)d_in[3];
    const float* b1 = (const float*)d_in[4];
    float* out = (float*)d_out;
    __bf16* xb = (__bf16*)d_ws;   // 64*8192*2 = 1 MB

    cvt_x<<<dim3(256), dim3(256), 0, stream>>>(x, xb);
    gat_gemm_elu11<<<dim3(OO / 32), dim3(512), 0, stream>>>(xb, W1, b1, out);
}